// Round 7
// baseline (403.286 us; speedup 1.0000x reference)
//
#include <hip/hip_runtime.h>
#include <math.h>

using short8   = __attribute__((ext_vector_type(8)))  short;
using floatx4  = __attribute__((ext_vector_type(4)))  float;
using floatx16 = __attribute__((ext_vector_type(16))) float;
using uintx4   = __attribute__((ext_vector_type(4)))  unsigned int;

#define AS1 __attribute__((address_space(1)))
#define AS3 __attribute__((address_space(3)))

__device__ __forceinline__ unsigned short f2bf(float f) {
  union { float f; unsigned int u; } v; v.f = f;
  unsigned int r = v.u + 0x7FFFu + ((v.u >> 16) & 1u);
  return (unsigned short)(r >> 16);
}
__device__ __forceinline__ void gload_lds16(const void* g, void* l) {
  __builtin_amdgcn_global_load_lds((const AS1 unsigned int*)g, (AS3 unsigned int*)l, 16, 0, 0);
}

#define B_  16
#define L_  4096
#define E_  128
#define F_  256
#define Y_  1000

// workspace offsets (bytes)
#define OFF_HLF   0u          // B*L*F bf16 = 32 MB (l,f) rows of 512B
#define OFF_UBF   33554432u   // 1024*256 bf16 (U padded)
#define OFF_FBF   34078720u   // 1024*256 bf16 (fc_w padded)
#define OFF_WBF   34603008u   // 3*256*128 bf16
#define OFF_PART  34799616u   // 16*8*8*128 float2 = 1 MB

// ---------------- K0: all repacks in one launch + zero the loss slot --------
__global__ __launch_bounds__(256) void k_repack(const float* __restrict__ Uw,
                                                const float* __restrict__ fcw,
                                                const float* __restrict__ cw,
                                                unsigned short* __restrict__ ubf,
                                                unsigned short* __restrict__ fbf,
                                                unsigned short* __restrict__ wbf,
                                                float* __restrict__ out) {
  const int bid = blockIdx.x, tid = threadIdx.x;
  if (bid == 0 && tid == 0) out[B_ * Y_] = 0.f;   // loss accumulator
  if (bid < 2048) {
    const float* src = (bid < 1024) ? Uw : fcw;
    unsigned short* dst = (bid < 1024) ? ubf : fbf;
    int i = (bid & 1023) * 256 + tid;
    int y = i >> 8, f = i & 255;
    float v = (y < Y_) ? src[y * F_ + f] : 0.f;
    dst[i] = f2bf(v);
  } else {
    int i = (bid - 2048) * 256 + tid;   // 32768 = 256*128
    const float* s = cw + (size_t)i * 3;
    wbf[0 * 32768 + i] = f2bf(s[0]);
    wbf[1 * 32768 + i] = f2bf(s[1]);
    wbf[2 * 32768 + i] = f2bf(s[2]);
  }
}

// ---------------- K1: fused embed-gather + conv1d(K=3,SAME) + bias + relu ----
// grid 2048 = 16b x 128 lgroups(32 l). Short phases: small halo tile (34 rows),
// acc 32 VGPR -> high occupancy to hide the random-gather latency.
#define ET_STR 272
__global__ __launch_bounds__(256, 4) void k_conv(const unsigned short* __restrict__ wbf,
                                                 const float* __restrict__ conv_b,
                                                 const int* __restrict__ x,
                                                 const float* __restrict__ ew,
                                                 unsigned short* __restrict__ hlf) {
  __shared__ unsigned char et[34 * ET_STR];  // 9248
  const int tid = threadIdx.x, bid = blockIdx.x;
  const int b = bid >> 7, l0 = (bid & 127) << 5;
  const int w = tid >> 6, lane = tid & 63, c = lane & 15, q = lane >> 4;
  const int* xb = x + b * L_;
  // gather + fp32->bf16 convert emb halo tile (34 rows x 128 e)
  for (int s = tid; s < 544; s += 256) {
    int row = s >> 4, sg = s & 15;
    int l = l0 - 1 + row;
    int idx = (l >= 0 && l < L_) ? xb[l] : 0;
    const float4* src = (const float4*)(ew + (size_t)idx * E_ + sg * 8);
    float4 a = src[0], bb = src[1];
    uintx4 v;
    v.x = (unsigned int)f2bf(a.x) | ((unsigned int)f2bf(a.y) << 16);
    v.y = (unsigned int)f2bf(a.z) | ((unsigned int)f2bf(a.w) << 16);
    v.z = (unsigned int)f2bf(bb.x) | ((unsigned int)f2bf(bb.y) << 16);
    v.w = (unsigned int)f2bf(bb.z) | ((unsigned int)f2bf(bb.w) << 16);
    *(uintx4*)(et + row * ET_STR + sg * 16) = v;
  }
  __syncthreads();
  const int fw = w * 64;
  floatx4 acc[2][4];
  #pragma unroll
  for (int ms = 0; ms < 2; ++ms)
    #pragma unroll
    for (int nt = 0; nt < 4; ++nt) acc[ms][nt] = (floatx4){0.f, 0.f, 0.f, 0.f};
  #pragma unroll
  for (int d = 0; d < 3; ++d)
    #pragma unroll
    for (int kq = 0; kq < 4; ++kq) {
      short8 aa[2], bb[4];
      #pragma unroll
      for (int ms = 0; ms < 2; ++ms)
        aa[ms] = *(const short8*)(et + (ms * 16 + c + d) * ET_STR + kq * 64 + q * 16);
      #pragma unroll
      for (int nt = 0; nt < 4; ++nt)
        bb[nt] = *(const short8*)((const unsigned char*)wbf +
                   ((size_t)(d * F_ + fw + nt * 16 + c) * E_ + kq * 32 + q * 8) * 2);
      #pragma unroll
      for (int ms = 0; ms < 2; ++ms)
        #pragma unroll
        for (int nt = 0; nt < 4; ++nt)
          acc[ms][nt] = __builtin_amdgcn_mfma_f32_16x16x32_bf16(aa[ms], bb[nt], acc[ms][nt], 0, 0, 0);
    }
  // epilogue: bias + relu, direct b16 stores (C: col=f@c, row=l@q*4+r)
  #pragma unroll
  for (int nt = 0; nt < 4; ++nt) {
    int f = fw + nt * 16 + c;
    float bias = conv_b[f];
    #pragma unroll
    for (int ms = 0; ms < 2; ++ms)
      #pragma unroll
      for (int r = 0; r < 4; ++r) {
        int l = l0 + ms * 16 + q * 4 + r;
        float v = acc[ms][nt][r] + bias;
        v = v > 0.f ? v : 0.f;
        hlf[((size_t)b * L_ + l) * F_ + f] = f2bf(v);
      }
  }
}

// ---------------- K2: fused attention (S and G share B-frags), Tl=32 --------
// r5 inner structure (124 VGPR, 0 conflicts) + 4 wg/CU via 8 L-chunks.
// grid 1024 = 16b x 8yt(128y) x 8chunks(512 l). mfma_32x32x16, dbuf 2x16KB.
__global__ __launch_bounds__(256, 4) void k_attn(const unsigned short* __restrict__ ubf,
                                                 const unsigned short* __restrict__ fbf,
                                                 const unsigned short* __restrict__ hlf,
                                                 float2* __restrict__ part) {
  __shared__ unsigned char lds[32768];
  const int tid = threadIdx.x;
  const int w = tid >> 6, lane = tid & 63, lo = lane & 31, hi = lane >> 5;
  const int bid = blockIdx.x;
  const int xcd = bid & 7, r0 = bid >> 3;
  const int b = xcd * 2 + (r0 & 1);               // 2 batches resident per XCD L2
  const int r2 = r0 >> 1, yt = r2 & 7, chunk = r2 >> 3;
  const int y0 = yt << 7, yw = y0 + w * 32;
  // A-frags resident: U and Fc rows for wave's 32 y, K=256 -> 16 k-steps
  short8 uf[16], ff[16];
  #pragma unroll
  for (int ks = 0; ks < 16; ++ks) {
    size_t off = ((size_t)(yw + lo) * F_ + ks * 16 + hi * 8) * 2;
    uf[ks] = *(const short8*)((const unsigned char*)ubf + off);
    ff[ks] = *(const short8*)((const unsigned char*)fbf + off);
  }
  float num[16], den[16];
  #pragma unroll
  for (int r = 0; r < 16; ++r) { num[r] = 0.f; den[r] = 0.f; }
  const unsigned char* hlfb = (const unsigned char*)hlf + (size_t)b * L_ * (F_ * 2);
  const int l0base = chunk << 9;

  // stage 16KB tile (32 l-rows x 512B) = 16 gll x 1KB; granule XOR-swizzle by row
#define STAGE(dstbuf, l0v)                                                      \
  {                                                                             \
    unsigned char* dstb = (dstbuf);                                             \
    _Pragma("unroll")                                                           \
    for (int ii = 0; ii < 4; ++ii) {                                            \
      int i = w * 4 + ii;                                                       \
      int r = 2 * i + hi;                                                       \
      int g = lo ^ r;                                                           \
      gload_lds16(hlfb + (size_t)((l0v) + r) * 512 + g * 16, dstb + i * 1024);  \
    }                                                                           \
  }

  STAGE(lds, l0base);
  __syncthreads();
  for (int it = 0; it < 16; ++it) {
    unsigned char* cur = lds + ((it & 1) << 14);
    if (it < 15) STAGE(lds + (((it & 1) ^ 1) << 14), l0base + (it + 1) * 32);
    floatx16 S = {0.f,0.f,0.f,0.f,0.f,0.f,0.f,0.f,0.f,0.f,0.f,0.f,0.f,0.f,0.f,0.f};
    floatx16 G = S;
    // B read: row(l)=lo, granule (ks*2+hi)^lo -> zero-conflict (r5-verified)
    #pragma unroll
    for (int ks = 0; ks < 16; ++ks) {
      short8 bb = *(const short8*)(cur + lo * 512 + (((ks * 2 + hi) ^ lo) << 4));
      S = __builtin_amdgcn_mfma_f32_32x32x16_bf16(uf[ks], bb, S, 0, 0, 0);
      G = __builtin_amdgcn_mfma_f32_32x32x16_bf16(ff[ks], bb, G, 0, 0, 0);
    }
    #pragma unroll
    for (int r = 0; r < 16; ++r) {
      float p = __expf(S[r]);
      num[r] += p * G[r];
      den[r] += p;
    }
    __syncthreads();
  }
  // reduce over the 32 l-columns (lanes lo within each hi-half)
  #pragma unroll
  for (int r = 0; r < 16; ++r) {
    float n = num[r], d = den[r];
    n += __shfl_xor(n, 1, 64);  d += __shfl_xor(d, 1, 64);
    n += __shfl_xor(n, 2, 64);  d += __shfl_xor(d, 2, 64);
    n += __shfl_xor(n, 4, 64);  d += __shfl_xor(d, 4, 64);
    n += __shfl_xor(n, 8, 64);  d += __shfl_xor(d, 8, 64);
    n += __shfl_xor(n, 16, 64); d += __shfl_xor(d, 16, 64);
    num[r] = n; den[r] = d;
  }
  float2* pb = part + (size_t)((b * 8 + yt) * 8 + chunk) * 128;
  if (lo == 0) {
    #pragma unroll
    for (int r = 0; r < 16; ++r) {
      int yl = w * 32 + (r & 3) + 8 * (r >> 2) + 4 * hi;  // 32x32 C/D row mapping
      float2 v; v.x = num[r]; v.y = den[r];
      pb[yl] = v;
    }
  }
}

// ---------------- K3: combine partials -> logits + CE loss (atomic mean) ----
__global__ __launch_bounds__(256) void k_logits(const float2* __restrict__ part,
                                                const float* __restrict__ fcb,
                                                const int* __restrict__ target,
                                                float* __restrict__ out) {
  __shared__ float red[4];
  const int b = blockIdx.x, tid = threadIdx.x;
  const int w = tid >> 6;
  float lg[4];
  #pragma unroll
  for (int k = 0; k < 4; ++k) {
    int y = tid + k * 256;
    int yt = y >> 7, yl = y & 127;
    float n = 0.f, la = 0.f;
    #pragma unroll
    for (int ch = 0; ch < 8; ++ch) {
      float2 v = part[(size_t)((b * 8 + yt) * 8 + ch) * 128 + yl];
      n += v.x; la += v.y;
    }
    float lv = (y < Y_) ? (n / la + fcb[y]) : -1e30f;
    lg[k] = lv;
    if (y < Y_) out[b * Y_ + y] = lv;
  }
  float m = fmaxf(fmaxf(lg[0], lg[1]), fmaxf(lg[2], lg[3]));
  for (int off = 1; off < 64; off <<= 1) m = fmaxf(m, __shfl_xor(m, off, 64));
  if ((tid & 63) == 0) red[w] = m;
  __syncthreads();
  m = fmaxf(fmaxf(red[0], red[1]), fmaxf(red[2], red[3]));
  __syncthreads();
  float s = 0.f;
  #pragma unroll
  for (int k = 0; k < 4; ++k)
    if (tid + k * 256 < Y_) s += __expf(lg[k] - m);
  for (int off = 1; off < 64; off <<= 1) s += __shfl_xor(s, off, 64);
  if ((tid & 63) == 0) red[w] = s;
  __syncthreads();
  s = red[0] + red[1] + red[2] + red[3];
  int t = target[b];
  #pragma unroll
  for (int k = 0; k < 4; ++k)
    if (tid + k * 256 == t)
      atomicAdd(&out[B_ * Y_], -(lg[k] - m - logf(s)) * (1.f / (float)B_));
}

// ---------------- launcher ----------------
extern "C" void kernel_launch(void* const* d_in, const int* in_sizes, int n_in,
                              void* d_out, int out_size, void* d_ws, size_t ws_size,
                              hipStream_t stream) {
  const int*   x       = (const int*)d_in[0];
  const int*   target  = (const int*)d_in[1];
  const float* embed_w = (const float*)d_in[2];
  const float* conv_w  = (const float*)d_in[3];
  const float* conv_b  = (const float*)d_in[4];
  const float* U_w     = (const float*)d_in[5];
  const float* fc_w    = (const float*)d_in[6];
  const float* fc_b    = (const float*)d_in[7];
  float* out = (float*)d_out;
  unsigned char* ws = (unsigned char*)d_ws;
  unsigned short* hlf  = (unsigned short*)(ws + OFF_HLF);
  unsigned short* ubf  = (unsigned short*)(ws + OFF_UBF);
  unsigned short* fbf  = (unsigned short*)(ws + OFF_FBF);
  unsigned short* wbf  = (unsigned short*)(ws + OFF_WBF);
  float2*         part = (float2*)(ws + OFF_PART);

  k_repack<<<2176, 256, 0, stream>>>(U_w, fc_w, conv_w, ubf, fbf, wbf, out);
  k_conv<<<2048, 256, 0, stream>>>(wbf, conv_b, x, embed_w, hlf);
  k_attn<<<1024, 256, 0, stream>>>(ubf, fbf, hlf, part);
  k_logits<<<16, 256, 0, stream>>>(part, fc_b, target, out);
}

// Round 8
// 199.921 us; speedup vs baseline: 2.0172x; 2.0172x over previous
//
#include <hip/hip_runtime.h>
#include <math.h>

using short8   = __attribute__((ext_vector_type(8)))  short;
using floatx4  = __attribute__((ext_vector_type(4)))  float;
using floatx16 = __attribute__((ext_vector_type(16))) float;
using uintx4   = __attribute__((ext_vector_type(4)))  unsigned int;

#define AS1 __attribute__((address_space(1)))
#define AS3 __attribute__((address_space(3)))

__device__ __forceinline__ unsigned short f2bf(float f) {
  union { float f; unsigned int u; } v; v.f = f;
  unsigned int r = v.u + 0x7FFFu + ((v.u >> 16) & 1u);
  return (unsigned short)(r >> 16);
}
__device__ __forceinline__ void gload_lds16(const void* g, void* l) {
  __builtin_amdgcn_global_load_lds((const AS1 unsigned int*)g, (AS3 unsigned int*)l, 16, 0, 0);
}

#define B_  16
#define L_  4096
#define E_  128
#define F_  256
#define Y_  1000

// workspace offsets (bytes)
#define OFF_HLF   0u          // B*L*F bf16 = 32 MB (l,f) rows of 512B
#define OFF_UBF   33554432u   // 1024*256 bf16 (U padded)
#define OFF_FBF   34078720u   // 1024*256 bf16 (fc_w padded)
#define OFF_WBF   34603008u   // 3*256*128 bf16
#define OFF_PART  34799616u   // 16*8*8*128 float2 = 1 MB

// ---------------- K0: all repacks in one launch + zero the loss slot --------
__global__ __launch_bounds__(256) void k_repack(const float* __restrict__ Uw,
                                                const float* __restrict__ fcw,
                                                const float* __restrict__ cw,
                                                unsigned short* __restrict__ ubf,
                                                unsigned short* __restrict__ fbf,
                                                unsigned short* __restrict__ wbf,
                                                float* __restrict__ out) {
  const int bid = blockIdx.x, tid = threadIdx.x;
  if (bid == 0 && tid == 0) out[B_ * Y_] = 0.f;   // loss accumulator
  if (bid < 2048) {
    const float* src = (bid < 1024) ? Uw : fcw;
    unsigned short* dst = (bid < 1024) ? ubf : fbf;
    int i = (bid & 1023) * 256 + tid;
    int y = i >> 8, f = i & 255;
    float v = (y < Y_) ? src[y * F_ + f] : 0.f;
    dst[i] = f2bf(v);
  } else {
    int i = (bid - 2048) * 256 + tid;   // 32768 = 256*128
    const float* s = cw + (size_t)i * 3;
    wbf[0 * 32768 + i] = f2bf(s[0]);
    wbf[1 * 32768 + i] = f2bf(s[1]);
    wbf[2 * 32768 + i] = f2bf(s[2]);
  }
}

// ---------------- K1: fused embed-gather + conv1d(K=3,SAME) + bias + relu ----
// grid 1024 = 16b x 64 lgroups(64 l). Wave owns 64 f. EXACT r5 config:
// launch_bounds(256,2): 256-VGPR cap (acc 64 + aa 16 + bb 16 fits, no spill).
#define ET_STR 272
__global__ __launch_bounds__(256, 2) void k_conv(const unsigned short* __restrict__ wbf,
                                                 const float* __restrict__ conv_b,
                                                 const int* __restrict__ x,
                                                 const float* __restrict__ ew,
                                                 unsigned short* __restrict__ hlf) {
  __shared__ unsigned char et[66 * ET_STR];  // 17952
  const int tid = threadIdx.x, bid = blockIdx.x;
  const int b = bid >> 6, l0 = (bid & 63) << 6;
  const int w = tid >> 6, lane = tid & 63, c = lane & 15, q = lane >> 4;
  const int* xb = x + b * L_;
  // gather + fp32->bf16 convert emb halo tile (66 rows x 128 e)
  for (int s = tid; s < 1056; s += 256) {
    int row = s >> 4, sg = s & 15;
    int l = l0 - 1 + row;
    int idx = (l >= 0 && l < L_) ? xb[l] : 0;
    const float4* src = (const float4*)(ew + (size_t)idx * E_ + sg * 8);
    float4 a = src[0], bb = src[1];
    uintx4 v;
    v.x = (unsigned int)f2bf(a.x) | ((unsigned int)f2bf(a.y) << 16);
    v.y = (unsigned int)f2bf(a.z) | ((unsigned int)f2bf(a.w) << 16);
    v.z = (unsigned int)f2bf(bb.x) | ((unsigned int)f2bf(bb.y) << 16);
    v.w = (unsigned int)f2bf(bb.z) | ((unsigned int)f2bf(bb.w) << 16);
    *(uintx4*)(et + row * ET_STR + sg * 16) = v;
  }
  __syncthreads();
  const int fw = w * 64;
  floatx4 acc[4][4];
  #pragma unroll
  for (int ms = 0; ms < 4; ++ms)
    #pragma unroll
    for (int nt = 0; nt < 4; ++nt) acc[ms][nt] = (floatx4){0.f, 0.f, 0.f, 0.f};
  #pragma unroll
  for (int d = 0; d < 3; ++d)
    #pragma unroll
    for (int kq = 0; kq < 4; ++kq) {
      short8 aa[4], bb[4];
      #pragma unroll
      for (int ms = 0; ms < 4; ++ms)
        aa[ms] = *(const short8*)(et + (ms * 16 + c + d) * ET_STR + kq * 64 + q * 16);
      #pragma unroll
      for (int nt = 0; nt < 4; ++nt)
        bb[nt] = *(const short8*)((const unsigned char*)wbf +
                   ((size_t)(d * F_ + fw + nt * 16 + c) * E_ + kq * 32 + q * 8) * 2);
      #pragma unroll
      for (int ms = 0; ms < 4; ++ms)
        #pragma unroll
        for (int nt = 0; nt < 4; ++nt)
          acc[ms][nt] = __builtin_amdgcn_mfma_f32_16x16x32_bf16(aa[ms], bb[nt], acc[ms][nt], 0, 0, 0);
    }
  // epilogue: bias + relu, direct b16 stores (C: col=f@c, row=l@q*4+r)
  #pragma unroll
  for (int nt = 0; nt < 4; ++nt) {
    int f = fw + nt * 16 + c;
    float bias = conv_b[f];
    #pragma unroll
    for (int ms = 0; ms < 4; ++ms)
      #pragma unroll
      for (int r = 0; r < 4; ++r) {
        int l = l0 + ms * 16 + q * 4 + r;
        float v = acc[ms][nt][r] + bias;
        v = v > 0.f ? v : 0.f;
        hlf[((size_t)b * L_ + l) * F_ + f] = f2bf(v);
      }
  }
}

// ---------------- K2: fused attention (S and G share B-frags), Tl=32 --------
// EXACT r5 inner body + launch_bounds(256,2) (124 VGPR, 0 conflicts, no spill).
// Only change vs r5: grid 1024 = 16b x 8yt x 8chunks(512 l) -> 4 wg/CU can be
// HW-resident (124 <= 128 VGPR for 4 waves/SIMD; LDS 4x32KB = 128 <= 160).
__global__ __launch_bounds__(256, 2) void k_attn(const unsigned short* __restrict__ ubf,
                                                 const unsigned short* __restrict__ fbf,
                                                 const unsigned short* __restrict__ hlf,
                                                 float2* __restrict__ part) {
  __shared__ unsigned char lds[32768];
  const int tid = threadIdx.x;
  const int w = tid >> 6, lane = tid & 63, lo = lane & 31, hi = lane >> 5;
  const int bid = blockIdx.x;
  const int xcd = bid & 7, r0 = bid >> 3;
  const int b = xcd * 2 + (r0 & 1);               // 2 batches resident per XCD L2
  const int r2 = r0 >> 1, yt = r2 & 7, chunk = r2 >> 3;
  const int y0 = yt << 7, yw = y0 + w * 32;
  // A-frags resident: U and Fc rows for wave's 32 y, K=256 -> 16 k-steps
  short8 uf[16], ff[16];
  #pragma unroll
  for (int ks = 0; ks < 16; ++ks) {
    size_t off = ((size_t)(yw + lo) * F_ + ks * 16 + hi * 8) * 2;
    uf[ks] = *(const short8*)((const unsigned char*)ubf + off);
    ff[ks] = *(const short8*)((const unsigned char*)fbf + off);
  }
  float num[16], den[16];
  #pragma unroll
  for (int r = 0; r < 16; ++r) { num[r] = 0.f; den[r] = 0.f; }
  const unsigned char* hlfb = (const unsigned char*)hlf + (size_t)b * L_ * (F_ * 2);
  const int l0base = chunk << 9;

  // stage 16KB tile (32 l-rows x 512B) = 16 gll x 1KB; granule XOR-swizzle by row
#define STAGE(dstbuf, l0v)                                                      \
  {                                                                             \
    unsigned char* dstb = (dstbuf);                                             \
    _Pragma("unroll")                                                           \
    for (int ii = 0; ii < 4; ++ii) {                                            \
      int i = w * 4 + ii;                                                       \
      int r = 2 * i + hi;                                                       \
      int g = lo ^ r;                                                           \
      gload_lds16(hlfb + (size_t)((l0v) + r) * 512 + g * 16, dstb + i * 1024);  \
    }                                                                           \
  }

  STAGE(lds, l0base);
  __syncthreads();
  for (int it = 0; it < 16; ++it) {
    unsigned char* cur = lds + ((it & 1) << 14);
    if (it < 15) STAGE(lds + (((it & 1) ^ 1) << 14), l0base + (it + 1) * 32);
    floatx16 S = {0.f,0.f,0.f,0.f,0.f,0.f,0.f,0.f,0.f,0.f,0.f,0.f,0.f,0.f,0.f,0.f};
    floatx16 G = S;
    // B read: row(l)=lo, granule (ks*2+hi)^lo -> zero-conflict (r5-verified)
    #pragma unroll
    for (int ks = 0; ks < 16; ++ks) {
      short8 bb = *(const short8*)(cur + lo * 512 + (((ks * 2 + hi) ^ lo) << 4));
      S = __builtin_amdgcn_mfma_f32_32x32x16_bf16(uf[ks], bb, S, 0, 0, 0);
      G = __builtin_amdgcn_mfma_f32_32x32x16_bf16(ff[ks], bb, G, 0, 0, 0);
    }
    #pragma unroll
    for (int r = 0; r < 16; ++r) {
      float p = __expf(S[r]);
      num[r] += p * G[r];
      den[r] += p;
    }
    __syncthreads();
  }
  // reduce over the 32 l-columns (lanes lo within each hi-half)
  #pragma unroll
  for (int r = 0; r < 16; ++r) {
    float n = num[r], d = den[r];
    n += __shfl_xor(n, 1, 64);  d += __shfl_xor(d, 1, 64);
    n += __shfl_xor(n, 2, 64);  d += __shfl_xor(d, 2, 64);
    n += __shfl_xor(n, 4, 64);  d += __shfl_xor(d, 4, 64);
    n += __shfl_xor(n, 8, 64);  d += __shfl_xor(d, 8, 64);
    n += __shfl_xor(n, 16, 64); d += __shfl_xor(d, 16, 64);
    num[r] = n; den[r] = d;
  }
  float2* pb = part + (size_t)((b * 8 + yt) * 8 + chunk) * 128;
  if (lo == 0) {
    #pragma unroll
    for (int r = 0; r < 16; ++r) {
      int yl = w * 32 + (r & 3) + 8 * (r >> 2) + 4 * hi;  // 32x32 C/D row mapping
      float2 v; v.x = num[r]; v.y = den[r];
      pb[yl] = v;
    }
  }
}

// ---------------- K3: combine partials -> logits + CE loss (atomic mean) ----
__global__ __launch_bounds__(256) void k_logits(const float2* __restrict__ part,
                                                const float* __restrict__ fcb,
                                                const int* __restrict__ target,
                                                float* __restrict__ out) {
  __shared__ float red[4];
  const int b = blockIdx.x, tid = threadIdx.x;
  const int w = tid >> 6;
  float lg[4];
  #pragma unroll
  for (int k = 0; k < 4; ++k) {
    int y = tid + k * 256;
    int yt = y >> 7, yl = y & 127;
    float n = 0.f, la = 0.f;
    #pragma unroll
    for (int ch = 0; ch < 8; ++ch) {
      float2 v = part[(size_t)((b * 8 + yt) * 8 + ch) * 128 + yl];
      n += v.x; la += v.y;
    }
    float lv = (y < Y_) ? (n / la + fcb[y]) : -1e30f;
    lg[k] = lv;
    if (y < Y_) out[b * Y_ + y] = lv;
  }
  float m = fmaxf(fmaxf(lg[0], lg[1]), fmaxf(lg[2], lg[3]));
  for (int off = 1; off < 64; off <<= 1) m = fmaxf(m, __shfl_xor(m, off, 64));
  if ((tid & 63) == 0) red[w] = m;
  __syncthreads();
  m = fmaxf(fmaxf(red[0], red[1]), fmaxf(red[2], red[3]));
  __syncthreads();
  float s = 0.f;
  #pragma unroll
  for (int k = 0; k < 4; ++k)
    if (tid + k * 256 < Y_) s += __expf(lg[k] - m);
  for (int off = 1; off < 64; off <<= 1) s += __shfl_xor(s, off, 64);
  if ((tid & 63) == 0) red[w] = s;
  __syncthreads();
  s = red[0] + red[1] + red[2] + red[3];
  int t = target[b];
  #pragma unroll
  for (int k = 0; k < 4; ++k)
    if (tid + k * 256 == t)
      atomicAdd(&out[B_ * Y_], -(lg[k] - m - logf(s)) * (1.f / (float)B_));
}

// ---------------- launcher ----------------
extern "C" void kernel_launch(void* const* d_in, const int* in_sizes, int n_in,
                              void* d_out, int out_size, void* d_ws, size_t ws_size,
                              hipStream_t stream) {
  const int*   x       = (const int*)d_in[0];
  const int*   target  = (const int*)d_in[1];
  const float* embed_w = (const float*)d_in[2];
  const float* conv_w  = (const float*)d_in[3];
  const float* conv_b  = (const float*)d_in[4];
  const float* U_w     = (const float*)d_in[5];
  const float* fc_w    = (const float*)d_in[6];
  const float* fc_b    = (const float*)d_in[7];
  float* out = (float*)d_out;
  unsigned char* ws = (unsigned char*)d_ws;
  unsigned short* hlf  = (unsigned short*)(ws + OFF_HLF);
  unsigned short* ubf  = (unsigned short*)(ws + OFF_UBF);
  unsigned short* fbf  = (unsigned short*)(ws + OFF_FBF);
  unsigned short* wbf  = (unsigned short*)(ws + OFF_WBF);
  float2*         part = (float2*)(ws + OFF_PART);

  k_repack<<<2176, 256, 0, stream>>>(U_w, fc_w, conv_w, ubf, fbf, wbf, out);
  k_conv<<<1024, 256, 0, stream>>>(wbf, conv_b, x, embed_w, hlf);
  k_attn<<<1024, 256, 0, stream>>>(ubf, fbf, hlf, part);
  k_logits<<<16, 256, 0, stream>>>(part, fc_b, target, out);
}